// Round 9
// baseline (28.216 us; speedup 1.0000x reference)
//
#include <hip/hip_runtime.h>

#define NCLS   80
#define NB     8
#define NGT    32
#define NANCH  36864                 // anchors per image (9*64*64)
#define APB    144                   // anchors per block: 294912 / 2048
#define NTHR   256
#define NBLK   2048                  // == 256 CU * 8 blocks/CU -> zero tail
#define BLKS_PER_IMG 256
#define F4PB   (APB * 20)            // 2880 float4 per block
#define KFULL  11                    // 11*256 = 2816
#define KREM   64                    // 2880 - 2816

#define LOG2E 1.4426950408889634f
#define LN2   0.6931471805599453f

// Anchor W/H computed in double (matches Python float arithmetic), cast to f32.
__device__ __constant__ float c_aw[9] = {
    (float)(32.0 * 1.0    * 1.0), (float)(32.0 * 1.0    * 1.4), (float)(32.0 * 1.0    * 0.7),
    (float)(32.0 * 1.2599 * 1.0), (float)(32.0 * 1.2599 * 1.4), (float)(32.0 * 1.2599 * 0.7),
    (float)(32.0 * 1.5874 * 1.0), (float)(32.0 * 1.5874 * 1.4), (float)(32.0 * 1.5874 * 0.7)};
__device__ __constant__ float c_ah[9] = {
    (float)(32.0 * 1.0    * 1.0), (float)(32.0 * 1.0    * 0.7), (float)(32.0 * 1.0    * 1.4),
    (float)(32.0 * 1.2599 * 1.0), (float)(32.0 * 1.2599 * 0.7), (float)(32.0 * 1.2599 * 1.4),
    (float)(32.0 * 1.5874 * 1.0), (float)(32.0 * 1.5874 * 0.7), (float)(32.0 * 1.5874 * 1.4)};

// One float4 partial per block: {cls_loss(l2 units scaled), xywh_loss, pos_count, 0}
__global__ __launch_bounds__(NTHR, 8) void retina_main(
    const float* __restrict__ t_xywh,      // [B, N, 4]
    const float* __restrict__ cls_logits,  // [B, N, 80]
    const float* __restrict__ gt_bboxes,   // [B, 32, 4] cxcywh
    const int*   __restrict__ gt_cats,     // [B, 32]
    float4* __restrict__ part)             // [NBLK]
{
    __shared__ int   s_flag[APB];     // -1: skip; 0..79: pos class; 256: neg-only
    __shared__ float s_red[4 * 3];

    const int tid = threadIdx.x;
    const int blk = blockIdx.x;
    const int b   = blk >> 8;              // image (256 blocks per image)
    const int s   = blk & 255;             // slice within image

    const float4* gt4  = (const float4*)gt_bboxes + b * NGT;
    const int*    gcat = gt_cats + b * NGT;

    // ---- IoU assignment: thread t owns anchor t (t < 144), all 32 GTs ----
    float lx = 0.0f, pcnt = 0.0f;
    if (tid < APB) {
        const int n  = s * APB + tid;      // anchor within image
        const int a  = n >> 12;
        const int hy = (n >> 6) & 63;
        const int wx = n & 63;
        const float acx = (wx + 0.5f) * 8.0f;
        const float acy = (hy + 0.5f) * 8.0f;
        const float aw  = c_aw[a];
        const float ah  = c_ah[a];

        float best = -1.0f;
        int   bi   = 0;
        {
            const float a_tlx = acx - aw * 0.5f, a_tly = acy - ah * 0.5f;
            const float a_brx = acx + aw * 0.5f, a_bry = acy + ah * 0.5f;
            const float area_a = aw * ah;
            for (int gg = 0; gg < NGT; ++gg) {
                const float4 gb = gt4[gg];           // wave-uniform -> s_load
                const float g_tlx = gb.x - gb.z * 0.5f, g_tly = gb.y - gb.w * 0.5f;
                const float g_brx = gb.x + gb.z * 0.5f, g_bry = gb.y + gb.w * 0.5f;
                float dx = fminf(a_brx, g_brx) - fmaxf(a_tlx, g_tlx);
                float dy = fminf(a_bry, g_bry) - fmaxf(a_tly, g_tly);
                dx = fmaxf(dx, 0.0f);
                dy = fmaxf(dy, 0.0f);
                const float inter = dx * dy;
                const float uni   = area_a + gb.z * gb.w - inter;
                const float iou   = inter * __builtin_amdgcn_rcpf(uni);
                if (iou > best) { best = iou; bi = gg; }   // strict > = first argmax
            }
        }

        const bool pos = best > 0.5f;
        const bool neg = best < 0.4f;
        int f = (pos | neg) ? 256 : -1;
        if (pos) {                                 // rare (~0.4% of anchors)
            f    = gcat[bi];
            pcnt = 1.0f;
            const float4 g = gt4[bi];
            const float4 t = ((const float4*)t_xywh)[(size_t)b * NANCH + n];
            const float tx = (g.x - acx) / aw;
            const float ty = (g.y - acy) / ah;
            const float tw = logf(g.z / aw + 1e-8f);
            const float th = logf(g.w / ah + 1e-8f);
            const float d0 = t.x - tx, d1 = t.y - ty, d2 = t.z - tw, d3 = t.w - th;
            lx = d0 * d0 + d1 * d1 + d2 * d2 + d3 * d3;
        }
        s_flag[tid] = f;
    }
    __syncthreads();   // nothing in flight to drain; streaming loads start AFTER this

    // ---- streaming BCE: softplus(x) = ln2 * log2(1 + 2^(x*log2e)) ----
    const float4* base = (const float4*)cls_logits + (size_t)blk * F4PB;
    float l2 = 0.0f, hot = 0.0f;

#define BCE_ELEM(E)                                                             \
    {                                                                           \
        const int e  = (E);                                                     \
        const int la = e / 20;               /* owning anchor (20 f4 each) */   \
        const float4 x = base[e];                                               \
        const int fl = s_flag[la];                                              \
        const float t0 = __builtin_amdgcn_exp2f(x.x * LOG2E);                   \
        const float t1 = __builtin_amdgcn_exp2f(x.y * LOG2E);                   \
        const float t2 = __builtin_amdgcn_exp2f(x.z * LOG2E);                   \
        const float t3 = __builtin_amdgcn_exp2f(x.w * LOG2E);                   \
        const float g0 = __builtin_amdgcn_logf(1.0f + t0);                      \
        const float g1 = __builtin_amdgcn_logf(1.0f + t1);                      \
        const float g2 = __builtin_amdgcn_logf(1.0f + t2);                      \
        const float g3 = __builtin_amdgcn_logf(1.0f + t3);                      \
        const float m  = (fl >= 0) ? 1.0f : 0.0f;                               \
        l2 += m * ((g0 + g1) + (g2 + g3));                                      \
        if (__any((unsigned)fl < NCLS)) {    /* positive anchors are rare */    \
            const int c0 = (e - la * 20) * 4;                                   \
            hot += (fl == c0    ) ? x.x : 0.0f;                                 \
            hot += (fl == c0 + 1) ? x.y : 0.0f;                                 \
            hot += (fl == c0 + 2) ? x.z : 0.0f;                                 \
            hot += (fl == c0 + 3) ? x.w : 0.0f;                                 \
        }                                                                       \
    }

#pragma unroll
    for (int k = 0; k < KFULL; ++k) BCE_ELEM(k * NTHR + tid)
    if (tid < KREM) BCE_ELEM(KFULL * NTHR + tid)   // remainder: wave 0 only
#undef BCE_ELEM

    const float lc = LN2 * l2 - hot;

    // ---- block reduction of (lc, lx, pcnt) ----
    float v0 = lc, v1 = lx, v2 = pcnt;
    for (int o = 32; o > 0; o >>= 1) {
        v0 += __shfl_down(v0, o);
        v1 += __shfl_down(v1, o);
        v2 += __shfl_down(v2, o);
    }
    const int wave = tid >> 6;
    if ((tid & 63) == 0) {
        s_red[wave * 3 + 0] = v0;
        s_red[wave * 3 + 1] = v1;
        s_red[wave * 3 + 2] = v2;
    }
    __syncthreads();
    if (tid == 0) {
        float c = 0.0f, xw = 0.0f, pc = 0.0f;
        for (int w2 = 0; w2 < 4; ++w2) {
            c  += s_red[w2 * 3 + 0];
            xw += s_red[w2 * 3 + 1];
            pc += s_red[w2 * 3 + 2];
        }
        part[blk] = make_float4(c, xw, pc, 0.0f);
    }
}

// ---- fold 2048 block partials into the scalar loss ----
__global__ __launch_bounds__(256) void retina_final(
    const float4* __restrict__ part, float* __restrict__ out)
{
    __shared__ float s_lc[NB], s_pc[NB], s_lx[NB];
    const int tid = threadIdx.x;
    const int b = tid >> 5, l = tid & 31;    // 32 lanes per image

    float lc = 0.0f, lx = 0.0f, pc = 0.0f;
    for (int i = l; i < BLKS_PER_IMG; i += 32) {
        const float4 p = part[b * BLKS_PER_IMG + i];
        lc += p.x; lx += p.y; pc += p.z;
    }
    for (int o = 16; o > 0; o >>= 1) {       // xor butterfly stays within the 32-group
        lc += __shfl_xor(lc, o);
        lx += __shfl_xor(lx, o);
        pc += __shfl_xor(pc, o);
    }
    if (l == 0) { s_lc[b] = lc; s_pc[b] = pc; s_lx[b] = lx; }
    __syncthreads();

    if (tid == 0) {
        float s = 0.0f, lxt = 0.0f;
        for (int bb = 0; bb < NB; ++bb) {
            lxt += s_lx[bb];
            s   += s_lc[bb] / (s_pc[bb] + 1.0f);
        }
        out[0] = (lxt + s) / (float)NB;
    }
}

extern "C" void kernel_launch(void* const* d_in, const int* in_sizes, int n_in,
                              void* d_out, int out_size, void* d_ws, size_t ws_size,
                              hipStream_t stream)
{
    const float* t_xywh     = (const float*)d_in[0];
    const float* cls_logits = (const float*)d_in[1];
    const float* gt_bboxes  = (const float*)d_in[2];
    const int*   gt_cats    = (const int*)d_in[3];

    float4* part = (float4*)d_ws;   // 2048 * 16 B = 32.8 KB

    retina_main<<<NBLK, NTHR, 0, stream>>>(t_xywh, cls_logits, gt_bboxes, gt_cats, part);
    retina_final<<<1, 256, 0, stream>>>(part, (float*)d_out);
}